// Round 13
// baseline (84.378 us; speedup 1.0000x reference)
//
#include <hip/hip_runtime.h>
#include <math.h>

#define B 1024
#define D 128
#define TDIM 1
#define NT 256

constexpr float THR   = 0.05f;
constexpr float LAM1f = 1.0f;
constexpr float LAM2f = 0.5f;
constexpr float EPSf  = 1e-8f;

struct SelOut { unsigned total, bucket, rem; };

// cooperative 256-thread radix-select over a 2048-bucket histogram (pure
// integer math on identical data -> bit-identical in every block). Works for
// global or LDS histograms (generic pointer).
__device__ SelOut block_select(const unsigned* h, unsigned kk_in) {
  int t = threadIdx.x;
  unsigned local[8];
  unsigned lsum = 0;
#pragma unroll
  for (int q = 0; q < 8; ++q) {
    unsigned v = h[t * 8 + q];
    local[q] = v; lsum += v;
  }
  unsigned incl = lsum;
#pragma unroll
  for (int o = 1; o < 64; o <<= 1) {
    unsigned nbr = __shfl_up(incl, o, 64);
    if ((t & 63) >= o) incl += nbr;
  }
  __shared__ unsigned sel_wsum[4];
  __shared__ unsigned sel_res[3];
  if ((t & 63) == 63) sel_wsum[t >> 6] = incl;
  __syncthreads();
  unsigned wpre = 0;
  for (int wv = 0; wv < (t >> 6); ++wv) wpre += sel_wsum[wv];
  incl += wpre;
  unsigned excl = incl - lsum;
  if (t == 255) sel_res[0] = incl;
  __syncthreads();
  unsigned total = sel_res[0];
  unsigned kk = (kk_in == 0xFFFFFFFFu) ? ((total ? total - 1u : 0u) >> 1) : kk_in;
  if (total && kk >= excl && kk < incl) {   // exactly one thread
    unsigned cum = excl;
    for (int q = 0; q < 8; ++q) {
      if (cum + local[q] > kk) { sel_res[1] = (unsigned)(t * 8 + q); sel_res[2] = kk - cum; break; }
      cum += local[q];
    }
  }
  __syncthreads();
  SelOut o; o.total = total; o.bucket = sel_res[1]; o.rem = sel_res[2];
  return o;
}

// ---- kA: column stats + zero h1 (b<128) ||
//          key segments + LDS h0 parts, 16 rows/block (128<=b<192) ----------
// No pre-zeroed global atomic targets needed in this dispatch.
__global__ void __launch_bounds__(NT) kA(const float* __restrict__ x,
                                         const float* __restrict__ y,
                                         float* __restrict__ m,
                                         float* __restrict__ s,
                                         unsigned* __restrict__ keys,
                                         unsigned* __restrict__ blockcnt,
                                         unsigned* __restrict__ hpart,
                                         unsigned* __restrict__ h1) {
  const int b = blockIdx.x, t = threadIdx.x;

  if (b < 128) {                       // ---- column mean/std (ddof=1) ----
    if (t < 16) h1[b * 16 + t] = 0u;   // zero h1 for kB's atomics (2048 total)
    const int c = b;
    float v[4];
#pragma unroll
    for (int k = 0; k < 4; ++k) v[k] = x[(t + k * 256) * D + c];
    __shared__ float red[NT];
    red[t] = v[0] + v[1] + v[2] + v[3];
    __syncthreads();
    for (int o = 128; o > 0; o >>= 1) {
      if (t < o) red[t] += red[t + o];
      __syncthreads();
    }
    __shared__ float mean_sh;
    if (t == 0) mean_sh = red[0] * (1.0f / 1024.0f);
    __syncthreads();
    float mean = mean_sh;
    float sq = 0.f;
#pragma unroll
    for (int k = 0; k < 4; ++k) { float dv = v[k] - mean; sq += dv * dv; }
    __syncthreads();
    red[t] = sq;
    __syncthreads();
    for (int o = 128; o > 0; o >>= 1) {
      if (t < o) red[t] += red[t + o];
      __syncthreads();
    }
    if (t == 0) {
      float var = red[0] * (1.0f / 1023.0f);
      float sd = sqrtf(var);
      if (sd < 1e-6f) sd = 1e-6f;
      m[c] = mean;
      s[c] = sd;
    }
    return;
  }

  // ---- key block: 16 rows; per-row ballot-compact -> global segment;
  //      LDS h0 histogram built during the same scan; non-atomic part dump --
  const int kb = b - 128;              // 0..63
  __shared__ float ysh[B];
  __shared__ float xc1[B];
  __shared__ unsigned keybuf[1024];
  __shared__ unsigned lh[2048];
  __shared__ unsigned wcnt[4];
  for (int j = t; j < B; j += NT) {
    ysh[j] = y[j];
    xc1[j] = x[j * D + TDIM];
  }
  for (int q = t; q < 2048; q += NT) lh[q] = 0;
  __syncthreads();
  const int lane = t & 63, wv = t >> 6;
  unsigned off = 0;
  unsigned* seg = keys + (size_t)kb * 16384;
  for (int rr = 0; rr < 16; ++rr) {
    int i = kb * 16 + rr;
    float yi = ysh[i], xi1 = xc1[i];
    unsigned base = 0;
    for (int rnd = 0; rnd < 4; ++rnd) {
      int j = rnd * NT + t;
      bool ok = (j != i) && (fabsf(yi - ysh[j]) <= THR);
      float dxr = xi1 - xc1[j];
      unsigned key = __float_as_uint(dxr * dxr);
      unsigned long long mk = __ballot(ok);
      if (lane == 0) wcnt[wv] = (unsigned)__popcll(mk);
      __syncthreads();
      unsigned pre = base;
      for (int w2 = 0; w2 < wv; ++w2) pre += wcnt[w2];
      if (ok) {
        unsigned mypos = (unsigned)__popcll(mk & ((1ull << lane) - 1ull));
        keybuf[pre + mypos] = key;
        atomicAdd(&lh[key >> 21], 1u);          // LDS histogram
      }
      base += wcnt[0] + wcnt[1] + wcnt[2] + wcnt[3];
      __syncthreads();
    }
    for (unsigned q = t; q < base; q += NT) seg[off + q] = keybuf[q];
    off += base;
    __syncthreads();                            // keybuf reuse next row
  }
  if (t == 0) blockcnt[kb] = off;
  for (int q = t; q < 2048; q += NT)
    hpart[(size_t)kb * 2048 + q] = lh[q];       // non-atomic dump
}

// ---- kB: h0 assemble + h1 from own key segment (b<64) ||
//          normalize (64<=b<576, 2 rows each) ------------------------------
__global__ void __launch_bounds__(NT) kB(const float* __restrict__ x,
                                         const float* __restrict__ m,
                                         const float* __restrict__ s,
                                         const unsigned* __restrict__ keys,
                                         const unsigned* __restrict__ blockcnt,
                                         const unsigned* __restrict__ hpart,
                                         unsigned* __restrict__ h0g,
                                         unsigned* __restrict__ h1,
                                         float* __restrict__ xn,
                                         float* __restrict__ z2,
                                         float* __restrict__ r2o) {
  const int b = blockIdx.x, t = threadIdx.x;
  if (b < 64) {
    __shared__ unsigned h0[2048];
    // assemble full h0 from 64 parts (8 KB useful; coalesced across t)
    for (int q = t; q < 2048; q += NT) {
      unsigned acc = 0;
#pragma unroll 4
      for (int p = 0; p < 64; ++p) acc += hpart[(size_t)p * 2048 + q];
      h0[q] = acc;
    }
    __syncthreads();
    if (b == 0)
      for (int q = t; q < 2048; q += NT) h0g[q] = h0[q];   // publish for kC
    SelOut s0 = block_select(h0, 0xFFFFFFFFu);
    if (s0.total == 0) return;          // h1 stays zeroed; kC guards on total
    // stream OWN pre-compacted key segment; filter bucket0 -> LDS h1 part
    __shared__ unsigned lh1[2048];
    for (int q = t; q < 2048; q += NT) lh1[q] = 0;
    __syncthreads();
    unsigned cnt = blockcnt[b];
    const unsigned* seg = keys + (size_t)b * 16384;
    for (unsigned q = t; q < cnt; q += NT) {
      unsigned bits = seg[q];
      if ((bits >> 21) == s0.bucket) atomicAdd(&lh1[(bits >> 10) & 0x7FFu], 1u);
    }
    __syncthreads();
    for (int q = t; q < 2048; q += NT) {
      unsigned c = lh1[q];
      if (c) atomicAdd(&h1[q], c);       // ~80 nonzero buckets/block
    }
    return;
  }
  const int pr = b - 64;               // 0..511, two rows each
  const int c = t & 127;
  const int row = 2 * pr + (t >> 7);
  float v = (x[row * D + c] - m[c]) / s[c];
  xn[row * D + c] = v;
  if (c == TDIM) z2[row] = v;
  __shared__ float red[NT];
  red[t] = (c != TDIM) ? v * v : 0.f;
  __syncthreads();
  for (int o = 64; o > 0; o >>= 1) {
    if ((t & 127) < o) red[t] += red[t + o];
    __syncthreads();
  }
  if ((t & 127) == 0) r2o[row] = red[t];
}

// ---- kC: pairwise pass (redundant 2-level select, 22-bit truncated T) ----
__global__ void __launch_bounds__(NT) kC(const float* __restrict__ y,
                                         const float* __restrict__ z2,
                                         const float* __restrict__ r2o,
                                         const float* __restrict__ xn,
                                         const float* __restrict__ s,
                                         const unsigned* __restrict__ h0,
                                         const unsigned* __restrict__ h1,
                                         float* __restrict__ loss_i,
                                         unsigned* __restrict__ haspos_i) {
  const int t = threadIdx.x;
  const int i = blockIdx.x;

  SelOut s0 = block_select(h0, 0xFFFFFFFFu);
  SelOut s1; s1.bucket = 0;
  if (s0.total) s1 = block_select(h1, s0.rem);   // block-uniform branch
  __shared__ float tb;
  if (t == 0) {
    if (s0.total) {
      // 22-bit truncated median key (raw (dx)^2 bits), rescaled by 1/s1^2.
      unsigned bits = (s0.bucket << 21) | (s1.bucket << 10);
      float inv = 1.0f / s[TDIM];
      tb = fmaxf(__uint_as_float(bits) * inv * inv, 1e-6f);
    } else tb = 2.0f;
  }
  __shared__ float xi_sh[D];
  if (t < D) xi_sh[t] = xn[i * D + t];
  __syncthreads();
  const float invT = 1.0f / tb;

  float yi = y[i], zi = z2[i], ri = r2o[i];

  // den1 over ALL j (j==i contributes exp(0)=1 exactly; removed after reduce)
  float4 zz = *(const float4*)(z2 + t * 4);
  float e0 = zi - zz.x, e1 = zi - zz.y, e2 = zi - zz.z, e3 = zi - zz.w;
  float den1 = __expf(-e0 * e0 * invT) + __expf(-e1 * e1 * invT)
             + __expf(-e2 * e2 * invT) + __expf(-e3 * e3 * invT);

  // deterministic ballot-compaction of same-age neighbors
  __shared__ unsigned short jlist[B];
  __shared__ unsigned wcnt_sh[4];
  unsigned base = 0;
  const int lane = t & 63, wv = t >> 6;
  for (int rnd = 0; rnd < 4; ++rnd) {
    int j = rnd * NT + t;
    bool ok = (j != i) && (fabsf(yi - y[j]) <= THR);
    unsigned long long mk = __ballot(ok);
    if (lane == 0) wcnt_sh[wv] = (unsigned)__popcll(mk);
    __syncthreads();
    unsigned pre = base;
    for (int w2 = 0; w2 < wv; ++w2) pre += wcnt_sh[w2];
    if (ok) {
      unsigned mypos = (unsigned)__popcll(mk & ((1ull << lane) - 1ull));
      jlist[pre + mypos] = (unsigned short)j;
    }
    base += wcnt_sh[0] + wcnt_sh[1] + wcnt_sh[2] + wcnt_sh[3];
    __syncthreads();
  }
  unsigned cnt = base;   // block-uniform, deterministic (sorted by j)

  float num = 0.f, den2 = 0.f;
  for (unsigned q = t; q < cnt; q += NT) {
    int j = jlist[q];
    float zj = z2[j];
    float dz = zi - zj;
    num += __expf(-dz * dz * invT);
    const float* xj = xn + j * D;
    float dot = 0.f;
#pragma unroll
    for (int d = 0; d < D; d += 4) {
      float4 a  = *(const float4*)(xi_sh + d);
      float4 bb = *(const float4*)(xj + d);
      dot += a.x * bb.x + a.y * bb.y + a.z * bb.z + a.w * bb.w;
    }
    float dot_o = dot - xi_sh[TDIM] * xj[TDIM];
    float sq = fmaxf((ri + r2o[j] - 2.f * dot_o) * (1.0f / 127.0f), 0.f);
    den2 += __expf(-sq * invT);
  }

  __shared__ float rn[NT], r1[NT], r2s[NT];
  rn[t] = num; r1[t] = den1; r2s[t] = den2;
  __syncthreads();
  for (int o = 128; o > 0; o >>= 1) {
    if (t < o) { rn[t] += rn[t + o]; r1[t] += r1[t + o]; r2s[t] += r2s[t + o]; }
    __syncthreads();
  }
  if (t == 0) {
    float den1t = r1[0] - 1.0f;               // remove j==i term
    float denom = LAM1f * den1t + LAM2f * r2s[0] + EPSf;
    float frac = fminf(fmaxf(rn[0] / denom, 1e-12f), 1.0f - 1e-7f);
    loss_i[i]   = (cnt > 0) ? -__logf(frac) : 0.f;
    haspos_i[i] = (cnt > 0) ? 1u : 0u;
  }
}

// ---- kD: final deterministic reduction ----
__global__ void __launch_bounds__(NT) kD(const float* __restrict__ loss_i,
                                         const unsigned* __restrict__ haspos_i,
                                         float* __restrict__ out) {
  __shared__ float rs[NT];
  __shared__ unsigned rcnt[NT];
  int t = threadIdx.x;
  float sv = 0.f;
  unsigned c = 0;
  for (int i = t; i < B; i += NT) { sv += loss_i[i]; c += haspos_i[i]; }
  rs[t] = sv; rcnt[t] = c;
  __syncthreads();
  for (int o = 128; o > 0; o >>= 1) {
    if (t < o) { rs[t] += rs[t + o]; rcnt[t] += rcnt[t + o]; }
    __syncthreads();
  }
  if (t == 0) out[0] = (rcnt[0] > 0) ? rs[0] / (float)rcnt[0] : 0.f;
}

extern "C" void kernel_launch(void* const* d_in, const int* in_sizes, int n_in,
                              void* d_out, int out_size, void* d_ws, size_t ws_size,
                              hipStream_t stream) {
  const float* x = (const float*)d_in[0];   // (1024,128) f32
  const float* y = (const float*)d_in[1];   // (1024,)    f32
  float* out = (float*)d_out;               // scalar f32

  char* w = (char*)d_ws;
  unsigned* h0g      = (unsigned*)(w + 0);        // 8 KB
  unsigned* h1       = (unsigned*)(w + 8192);     // 8 KB
  float*    m        = (float*)(w + 16384);       // 512 B
  float*    s        = (float*)(w + 16896);       // 512 B
  float*    z2       = (float*)(w + 17408);       // 4 KB (16B aligned)
  float*    r2o      = (float*)(w + 21504);       // 4 KB
  float*    loss_i   = (float*)(w + 25600);       // 4 KB
  unsigned* haspos_i = (unsigned*)(w + 29696);    // 4 KB
  unsigned* blockcnt = (unsigned*)(w + 33792);    // 1 KB (64 used)
  float*    xn       = (float*)(w + 34816);       // 512 KB
  unsigned* hpart    = (unsigned*)(w + 559104);   // 512 KB (64 x 2048 u32)
  unsigned* keys     = (unsigned*)(w + 1083392);  // 4 MB (64 segs x 16384 u32)

  kA<<<192, NT, 0, stream>>>(x, y, m, s, keys, blockcnt, hpart, h1);
  kB<<<576, NT, 0, stream>>>(x, m, s, keys, blockcnt, hpart, h0g, h1,
                             xn, z2, r2o);
  kC<<<B, NT, 0, stream>>>(y, z2, r2o, xn, s, h0g, h1, loss_i, haspos_i);
  kD<<<1, NT, 0, stream>>>(loss_i, haspos_i, out);
}

// Round 14
// 51.711 us; speedup vs baseline: 1.6317x; 1.6317x over previous
//
#include <hip/hip_runtime.h>
#include <math.h>

#define B 1024
#define D 128
#define TDIM 1
#define NT 256

constexpr float THR   = 0.05f;
constexpr float LAM1f = 1.0f;
constexpr float LAM2f = 0.5f;
constexpr float EPSf  = 1e-8f;

struct SelOut { unsigned total, bucket, rem; };

// cooperative 256-thread radix-select over a 2048-bucket histogram (pure
// integer math on identical global data -> bit-identical in every block)
__device__ SelOut block_select(const unsigned* __restrict__ h, unsigned kk_in) {
  int t = threadIdx.x;
  unsigned local[8];
  unsigned lsum = 0;
#pragma unroll
  for (int q = 0; q < 8; ++q) {
    unsigned v = h[t * 8 + q];
    local[q] = v; lsum += v;
  }
  unsigned incl = lsum;
#pragma unroll
  for (int o = 1; o < 64; o <<= 1) {
    unsigned nbr = __shfl_up(incl, o, 64);
    if ((t & 63) >= o) incl += nbr;
  }
  __shared__ unsigned sel_wsum[4];
  __shared__ unsigned sel_res[3];
  if ((t & 63) == 63) sel_wsum[t >> 6] = incl;
  __syncthreads();
  unsigned wpre = 0;
  for (int wv = 0; wv < (t >> 6); ++wv) wpre += sel_wsum[wv];
  incl += wpre;
  unsigned excl = incl - lsum;
  if (t == 255) sel_res[0] = incl;
  __syncthreads();
  unsigned total = sel_res[0];
  unsigned kk = (kk_in == 0xFFFFFFFFu) ? ((total ? total - 1u : 0u) >> 1) : kk_in;
  if (total && kk >= excl && kk < incl) {   // exactly one thread
    unsigned cum = excl;
    for (int q = 0; q < 8; ++q) {
      if (cum + local[q] > kk) { sel_res[1] = (unsigned)(t * 8 + q); sel_res[2] = kk - cum; break; }
      cum += local[q];
    }
  }
  __syncthreads();
  SelOut o; o.total = total; o.bucket = sel_res[1]; o.rem = sel_res[2];
  return o;
}

// ---- k0: zero h0+h1 (4096 u32) ----
__global__ void __launch_bounds__(NT) k0(unsigned* __restrict__ zb) {
  for (int i = threadIdx.x; i < 4096; i += NT) zb[i] = 0u;
}

// ---- kA: column stats (b<128) || key segments + h0 merge (128<=b<384) ----
__global__ void __launch_bounds__(NT) kA(const float* __restrict__ x,
                                         const float* __restrict__ y,
                                         float* __restrict__ m,
                                         float* __restrict__ s,
                                         unsigned* __restrict__ keys,
                                         unsigned* __restrict__ blockcnt,
                                         unsigned* __restrict__ h0) {
  const int b = blockIdx.x, t = threadIdx.x;

  if (b < 128) {                       // ---- column mean/std (ddof=1) ----
    const int c = b;
    float v[4];
#pragma unroll
    for (int k = 0; k < 4; ++k) v[k] = x[(t + k * 256) * D + c];
    __shared__ float red[NT];
    red[t] = v[0] + v[1] + v[2] + v[3];
    __syncthreads();
    for (int o = 128; o > 0; o >>= 1) {
      if (t < o) red[t] += red[t + o];
      __syncthreads();
    }
    __shared__ float mean_sh;
    if (t == 0) mean_sh = red[0] * (1.0f / 1024.0f);
    __syncthreads();
    float mean = mean_sh;
    float sq = 0.f;
#pragma unroll
    for (int k = 0; k < 4; ++k) { float dv = v[k] - mean; sq += dv * dv; }
    __syncthreads();
    red[t] = sq;
    __syncthreads();
    for (int o = 128; o > 0; o >>= 1) {
      if (t < o) red[t] += red[t + o];
      __syncthreads();
    }
    if (t == 0) {
      float var = red[0] * (1.0f / 1023.0f);
      float sd = sqrtf(var);
      if (sd < 1e-6f) sd = 1e-6f;
      m[c] = mean;
      s[c] = sd;
    }
    return;
  }

  // ---- key block: 4 rows, ballot-compact keys into segment + LDS h0 ----
  const int kb = b - 128;              // 0..255
  __shared__ float ysh[B];
  __shared__ float xc1[B];
  __shared__ unsigned keybuf[4096];
  __shared__ unsigned lh[2048];
  __shared__ unsigned wcnt[4];
  for (int j = t; j < B; j += NT) {
    ysh[j] = y[j];
    xc1[j] = x[j * D + TDIM];
  }
  for (int q = t; q < 2048; q += NT) lh[q] = 0;
  __syncthreads();
  const int lane = t & 63, wv = t >> 6;
  unsigned base = 0;
  for (int rr = 0; rr < 4; ++rr) {
    int i = kb * 4 + rr;
    float yi = ysh[i], xi1 = xc1[i];
    for (int rnd = 0; rnd < 4; ++rnd) {
      int j = rnd * NT + t;
      bool ok = (j != i) && (fabsf(yi - ysh[j]) <= THR);
      float dxr = xi1 - xc1[j];
      unsigned key = __float_as_uint(dxr * dxr);
      unsigned long long mk = __ballot(ok);
      if (lane == 0) wcnt[wv] = (unsigned)__popcll(mk);
      __syncthreads();
      unsigned pre = base;
      for (int w2 = 0; w2 < wv; ++w2) pre += wcnt[w2];
      if (ok) {
        unsigned mypos = (unsigned)__popcll(mk & ((1ull << lane) - 1ull));
        keybuf[pre + mypos] = key;
      }
      base += wcnt[0] + wcnt[1] + wcnt[2] + wcnt[3];
      __syncthreads();
    }
  }
  unsigned* seg = keys + (size_t)kb * 4096;
  for (unsigned q = t; q < base; q += NT) {
    unsigned k = keybuf[q];
    seg[q] = k;                         // coalesced
    atomicAdd(&lh[k >> 21], 1u);        // LDS atomic
  }
  if (t == 0) blockcnt[kb] = base;
  __syncthreads();
  for (int q = t; q < 2048; q += NT) {
    unsigned c = lh[q];
    if (c) atomicAdd(&h0[q], c);        // ~80 nonzero buckets/block
  }
}

// ---- kB: h1 (b<64, stream keys) || normalize (64<=b<576, 2 rows each) ----
__global__ void __launch_bounds__(NT) kB(const float* __restrict__ x,
                                         const float* __restrict__ m,
                                         const float* __restrict__ s,
                                         const unsigned* __restrict__ keys,
                                         const unsigned* __restrict__ blockcnt,
                                         const unsigned* __restrict__ h0,
                                         unsigned* __restrict__ h1,
                                         float* __restrict__ xn,
                                         float* __restrict__ z2,
                                         float* __restrict__ r2o) {
  const int b = blockIdx.x, t = threadIdx.x;
  if (b < 64) {
    SelOut s0 = block_select(h0, 0xFFFFFFFFu);
    if (s0.total == 0) return;         // h1 stays zeroed; kC guards on total
    __shared__ unsigned lh[2048];
    for (int q = t; q < 2048; q += NT) lh[q] = 0;
    __syncthreads();
    for (int sg = b; sg < 256; sg += 64) {
      unsigned cnt = blockcnt[sg];
      const unsigned* kp = keys + (size_t)sg * 4096;
      for (unsigned q = t; q < cnt; q += NT) {
        unsigned bits = kp[q];
        if ((bits >> 21) == s0.bucket) atomicAdd(&lh[(bits >> 10) & 0x7FFu], 1u);
      }
    }
    __syncthreads();
    for (int q = t; q < 2048; q += NT) {
      unsigned c = lh[q];
      if (c) atomicAdd(&h1[q], c);
    }
    return;
  }
  const int pr = b - 64;               // 0..511, two rows each
  const int half = t >> 7, c = t & 127;
  const int row = 2 * pr + half;
  float v = (x[row * D + c] - m[c]) / s[c];
  xn[row * D + c] = v;
  if (c == TDIM) z2[row] = v;
  __shared__ float red[NT];
  red[t] = (c != TDIM) ? v * v : 0.f;
  __syncthreads();
  for (int o = 64; o > 0; o >>= 1) {
    if ((t & 127) < o) red[t] += red[t + o];
    __syncthreads();
  }
  if ((t & 127) == 0) r2o[row] = red[t];
  (void)half;
}

// ---- kC: pairwise pass (redundant 2-level select, 22-bit truncated T) ----
__global__ void __launch_bounds__(NT) kC(const float* __restrict__ y,
                                         const float* __restrict__ z2,
                                         const float* __restrict__ r2o,
                                         const float* __restrict__ xn,
                                         const float* __restrict__ s,
                                         const unsigned* __restrict__ h0,
                                         const unsigned* __restrict__ h1,
                                         float* __restrict__ loss_i,
                                         unsigned* __restrict__ haspos_i) {
  const int t = threadIdx.x;
  const int i = blockIdx.x;

  SelOut s0 = block_select(h0, 0xFFFFFFFFu);
  SelOut s1; s1.bucket = 0;
  if (s0.total) s1 = block_select(h1, s0.rem);   // block-uniform branch
  __shared__ float tb;
  if (t == 0) {
    if (s0.total) {
      // 22-bit truncated median key (raw (dx)^2 bits), rescaled by 1/s1^2.
      // Relative error <= 2^-13 -> loss error ~1e-4, far below threshold.
      unsigned bits = (s0.bucket << 21) | (s1.bucket << 10);
      float inv = 1.0f / s[TDIM];
      tb = fmaxf(__uint_as_float(bits) * inv * inv, 1e-6f);
    } else tb = 2.0f;
  }
  __shared__ float xi_sh[D];
  if (t < D) xi_sh[t] = xn[i * D + t];
  __syncthreads();
  const float invT = 1.0f / tb;

  float yi = y[i], zi = z2[i], ri = r2o[i];

  // den1 over ALL j (j==i contributes exp(0)=1 exactly; removed after reduce)
  float4 zz = *(const float4*)(z2 + t * 4);
  float e0 = zi - zz.x, e1 = zi - zz.y, e2 = zi - zz.z, e3 = zi - zz.w;
  float den1 = __expf(-e0 * e0 * invT) + __expf(-e1 * e1 * invT)
             + __expf(-e2 * e2 * invT) + __expf(-e3 * e3 * invT);

  // deterministic ballot-compaction of same-age neighbors
  __shared__ unsigned short jlist[B];
  __shared__ unsigned wcnt_sh[4];
  unsigned base = 0;
  const int lane = t & 63, wv = t >> 6;
  for (int rnd = 0; rnd < 4; ++rnd) {
    int j = rnd * NT + t;
    bool ok = (j != i) && (fabsf(yi - y[j]) <= THR);
    unsigned long long mk = __ballot(ok);
    if (lane == 0) wcnt_sh[wv] = (unsigned)__popcll(mk);
    __syncthreads();
    unsigned pre = base;
    for (int w2 = 0; w2 < wv; ++w2) pre += wcnt_sh[w2];
    if (ok) {
      unsigned mypos = (unsigned)__popcll(mk & ((1ull << lane) - 1ull));
      jlist[pre + mypos] = (unsigned short)j;
    }
    base += wcnt_sh[0] + wcnt_sh[1] + wcnt_sh[2] + wcnt_sh[3];
    __syncthreads();
  }
  unsigned cnt = base;   // block-uniform, deterministic (sorted by j)

  float num = 0.f, den2 = 0.f;
  for (unsigned q = t; q < cnt; q += NT) {
    int j = jlist[q];
    float zj = z2[j];
    float dz = zi - zj;
    num += __expf(-dz * dz * invT);
    const float* xj = xn + j * D;
    float dot = 0.f;
#pragma unroll
    for (int d = 0; d < D; d += 4) {
      float4 a  = *(const float4*)(xi_sh + d);
      float4 bb = *(const float4*)(xj + d);
      dot += a.x * bb.x + a.y * bb.y + a.z * bb.z + a.w * bb.w;
    }
    float dot_o = dot - xi_sh[TDIM] * xj[TDIM];
    float sq = fmaxf((ri + r2o[j] - 2.f * dot_o) * (1.0f / 127.0f), 0.f);
    den2 += __expf(-sq * invT);
  }

  __shared__ float rn[NT], r1[NT], r2s[NT];
  rn[t] = num; r1[t] = den1; r2s[t] = den2;
  __syncthreads();
  for (int o = 128; o > 0; o >>= 1) {
    if (t < o) { rn[t] += rn[t + o]; r1[t] += r1[t + o]; r2s[t] += r2s[t + o]; }
    __syncthreads();
  }
  if (t == 0) {
    float den1t = r1[0] - 1.0f;               // remove j==i term
    float denom = LAM1f * den1t + LAM2f * r2s[0] + EPSf;
    float frac = fminf(fmaxf(rn[0] / denom, 1e-12f), 1.0f - 1e-7f);
    loss_i[i]   = (cnt > 0) ? -__logf(frac) : 0.f;
    haspos_i[i] = (cnt > 0) ? 1u : 0u;
  }
}

// ---- kD: final deterministic reduction ----
__global__ void __launch_bounds__(NT) kD(const float* __restrict__ loss_i,
                                         const unsigned* __restrict__ haspos_i,
                                         float* __restrict__ out) {
  __shared__ float rs[NT];
  __shared__ unsigned rcnt[NT];
  int t = threadIdx.x;
  float sv = 0.f;
  unsigned c = 0;
  for (int i = t; i < B; i += NT) { sv += loss_i[i]; c += haspos_i[i]; }
  rs[t] = sv; rcnt[t] = c;
  __syncthreads();
  for (int o = 128; o > 0; o >>= 1) {
    if (t < o) { rs[t] += rs[t + o]; rcnt[t] += rcnt[t + o]; }
    __syncthreads();
  }
  if (t == 0) out[0] = (rcnt[0] > 0) ? rs[0] / (float)rcnt[0] : 0.f;
}

extern "C" void kernel_launch(void* const* d_in, const int* in_sizes, int n_in,
                              void* d_out, int out_size, void* d_ws, size_t ws_size,
                              hipStream_t stream) {
  const float* x = (const float*)d_in[0];   // (1024,128) f32
  const float* y = (const float*)d_in[1];   // (1024,)    f32
  float* out = (float*)d_out;               // scalar f32

  char* w = (char*)d_ws;
  unsigned* zb       = (unsigned*)w;             // h0[2048] | h1[2048]
  unsigned* h0       = zb;
  unsigned* h1       = zb + 2048;
  float*    m        = (float*)(w + 16384);      // 512 B
  float*    s        = (float*)(w + 16896);      // 512 B
  float*    z2       = (float*)(w + 17408);      // 4 KB (16B aligned)
  float*    r2o      = (float*)(w + 21504);      // 4 KB
  unsigned* blockcnt = (unsigned*)(w + 25600);   // 1 KB
  float*    loss_i   = (float*)(w + 26624);      // 4 KB
  unsigned* haspos_i = (unsigned*)(w + 30720);   // 4 KB
  float*    xn       = (float*)(w + 34816);      // 512 KB
  unsigned* keys     = (unsigned*)(w + 559104);  // 4 MB (256 segs x 4096 u32)

  k0<<<1, NT, 0, stream>>>(zb);
  kA<<<384, NT, 0, stream>>>(x, y, m, s, keys, blockcnt, h0);
  kB<<<576, NT, 0, stream>>>(x, m, s, keys, blockcnt, h0, h1, xn, z2, r2o);
  kC<<<B, NT, 0, stream>>>(y, z2, r2o, xn, s, h0, h1, loss_i, haspos_i);
  kD<<<1, NT, 0, stream>>>(loss_i, haspos_i, out);
}